// Round 7
// baseline (530.010 us; speedup 1.0000x reference)
//
#include <hip/hip_runtime.h>
#include <stdint.h>

#define N_NODES 50000
#define N_EDGES 600000
#define DIM 128
#define NGRAPH 128
#define POOL_ROWS 100

typedef __bf16 bf16x8 __attribute__((ext_vector_type(8)));
typedef __bf16 bf16x2 __attribute__((ext_vector_type(2)));
typedef float f32x4 __attribute__((ext_vector_type(4)));
typedef unsigned short u16;
typedef unsigned int u32;
typedef long long i64;

typedef __attribute__((address_space(3))) char lds_char;
typedef __attribute__((address_space(3))) unsigned int lds_u32;
typedef const __attribute__((address_space(1))) unsigned int glb_cu32;

#if __has_builtin(__builtin_amdgcn_fdot2_f32_bf16)
#define HAS_FDOT2 1
#else
#define HAS_FDOT2 0
#endif

__device__ __forceinline__ float bf2f(u16 a) {
  union { u32 u; float f; } x; x.u = ((u32)a) << 16; return x.f;
}
__device__ __forceinline__ u16 f2bf(float f) {
  union { float f; u32 u; } x; x.f = f;
  u32 u = x.u;
  u32 r = (u + 0x7FFFu + ((u >> 16) & 1u)) >> 16;
  return (u16)r;
}
__device__ __forceinline__ void unpack8(uint4 v, float* f) {
  f[0] = bf2f((u16)(v.x & 0xFFFF)); f[1] = bf2f((u16)(v.x >> 16));
  f[2] = bf2f((u16)(v.y & 0xFFFF)); f[3] = bf2f((u16)(v.y >> 16));
  f[4] = bf2f((u16)(v.z & 0xFFFF)); f[5] = bf2f((u16)(v.z >> 16));
  f[6] = bf2f((u16)(v.w & 0xFFFF)); f[7] = bf2f((u16)(v.w >> 16));
}

// async global->LDS, 16B per lane; dest = uniform base + lane*16 (HW rule)
__device__ __forceinline__ void gll16(const void* g, lds_char* l) {
  __builtin_amdgcn_global_load_lds((glb_cu32*)g, (lds_u32*)l, 16, 0, 0);
}

// DPP row-level add: p + dpp(p). CTRL compile-time: 0xB1=quad xor1,
// 0x4E=quad xor2, 0x124=row_ror:4, 0x128=row_ror:8 (within 16-lane row).
template <int CTRL>
__device__ __forceinline__ float dpp_add(float p) {
  int t = __builtin_amdgcn_update_dpp(0, __float_as_int(p), CTRL, 0xf, 0xf, true);
  return p + __int_as_float(t);
}

// ---------------- sentinel (fp32 out) ----------------
__global__ void sentinel_fill(float* __restrict__ out, int n, float code) {
  int i = blockIdx.x * 256 + threadIdx.x;
  if (i < n) out[i] = code;
}

// ---------------- dtype detection (parallel) ----------------
__global__ void detect_dtypes(const u16* __restrict__ xu, const int* __restrict__ ei,
                              const int* __restrict__ bat, int* __restrict__ flags) {
  int gid = blockIdx.x * 256 + threadIdx.x;    // 32768 threads
  int c0 = 0;
  for (int i = gid; i < 200000; i += 32768) c0 += ((xu[i] & 0x7F80) == 0x7F80) ? 1 : 0;
  if (c0) atomicAdd(&flags[0], c0);
  if (gid < 2048 && ei[1 + gid * 586] != 0) atomicAdd(&flags[1], 1);
  if (gid < 2000 && bat[1 + gid * 24] != 0) atomicAdd(&flags[2], 1);
}

__device__ __forceinline__ void load_edge(const int* __restrict__ ei, bool is64, int e,
                                          int& s, int& d) {
  if (is64) {
    s = (int)((const i64*)ei)[e];
    d = (int)((const i64*)ei)[(size_t)N_EDGES + e];
  } else {
    s = ei[e];
    d = ei[N_EDGES + e];
  }
  s = min(max(s, 0), N_NODES - 1);
  d = min(max(d, 0), N_NODES - 1);
}

// ---------------- x → bf16 Hb (once) ----------------
__global__ void convert_x(const void* __restrict__ x, const int* __restrict__ flags,
                          u16* __restrict__ Hb) {
  int i = blockIdx.x * 256 + threadIdx.x;     // 8-elem chunk id
  const int total = N_NODES * DIM / 8;        // 800000
  if (i >= total) return;
  union { u16 h[8]; uint4 q; } pk;
  if (flags[0] > 0) {
    const float4* xf = (const float4*)x;
    float4 a = xf[(size_t)i * 2], b = xf[(size_t)i * 2 + 1];
    pk.h[0] = f2bf(a.x); pk.h[1] = f2bf(a.y); pk.h[2] = f2bf(a.z); pk.h[3] = f2bf(a.w);
    pk.h[4] = f2bf(b.x); pk.h[5] = f2bf(b.y); pk.h[6] = f2bf(b.z); pk.h[7] = f2bf(b.w);
  } else {
    pk.q = ((const uint4*)x)[i];
  }
  ((uint4*)Hb)[i] = pk.q;
}

// ---------------- weight prep: WT[(l*4+m)][j*128+k] = bf16(W[k][j]) ----------
__global__ void prep_wt(const void* __restrict__ Wq, const void* __restrict__ Wk,
                        const void* __restrict__ Wv, const void* __restrict__ Ws,
                        u16* __restrict__ WT, const int* __restrict__ flags) {
  int b = blockIdx.x;            // 0..11 = l*4+m
  int l = b >> 2, m = b & 3;
  bool f32 = flags[0] > 0;
  const void* W = (m == 0 ? Wq : m == 1 ? Wk : m == 2 ? Wv : Ws);
  size_t base = (size_t)l * DIM * DIM;
  u16* out = WT + (size_t)b * DIM * DIM;
  for (int idx = threadIdx.x; idx < DIM * DIM; idx += 256) {
    int j = idx >> 7, k = idx & 127;
    float v;
    if (f32) v = ((const float*)W)[base + (size_t)k * DIM + j];
    else     v = bf2f(((const u16*)W)[base + (size_t)k * DIM + j]);
    out[idx] = f2bf(v);
  }
}

__global__ void canon_bias(const void* __restrict__ bq, const void* __restrict__ bk,
                           const void* __restrict__ bv, const void* __restrict__ bs,
                           float* __restrict__ biasc, const int* __restrict__ flags) {
  bool f32 = flags[0] > 0;
  for (int idx = threadIdx.x; idx < 12 * DIM; idx += 256) {
    int b = idx >> 7, d = idx & 127;
    int l = b >> 2, m = b & 3;
    const void* p = (m == 0 ? bq : m == 1 ? bk : m == 2 ? bv : bs);
    float v;
    if (f32) v = ((const float*)p)[l * DIM + d];
    else     v = bf2f(((const u16*)p)[l * DIM + d]);
    biasc[idx] = v;
  }
}

// ---------------- fused q/k/v/skip GEMM: bf16 H, one matrix per block ----------
// K and V are written interleaved into KV: row n = [K(n) | V(n)] (512 B) so the
// attention gather touches one contiguous region per edge.
__global__ __launch_bounds__(256) void gemm_qkvs(
    const u16* __restrict__ Hb, const u16* __restrict__ WT,
    const float* __restrict__ biasc,
    u16* __restrict__ Q, u16* __restrict__ KV, u16* __restrict__ S) {
  __shared__ u16 As[64][136];    // 17.4 KB
  __shared__ u16 Bs[128][136];   // 34.8 KB
  int tid = threadIdx.x;
  int r0 = blockIdx.x * 64;
  int mat = blockIdx.y;
  const u16* Wt = WT + (size_t)mat * DIM * DIM;

  for (int it = 0; it < 4; ++it) {
    int i16 = it * 256 + tid;
    int row = i16 >> 4, seg = i16 & 15;
    uint4 val = make_uint4(0, 0, 0, 0);
    if (r0 + row < N_NODES) val = ((const uint4*)Hb)[(size_t)(r0 + row) * 16 + seg];
    *((uint4*)&As[row][seg * 8]) = val;
  }
  for (int it = 0; it < 8; ++it) {
    int i16 = it * 256 + tid;
    int j = i16 >> 4, seg = i16 & 15;
    uint4 val = ((const uint4*)Wt)[j * 16 + seg];
    *((uint4*)&Bs[j][seg * 8]) = val;
  }
  __syncthreads();

  int lane = tid & 63;
  int w = tid >> 6;
  int wm = w & 1, wn = w >> 1;
  int lrow = lane & 15;
  int kq = (lane >> 4) * 8;
  f32x4 acc[2][4] = {};
#pragma unroll
  for (int kt = 0; kt < 4; ++kt) {
    int k0 = kt * 32 + kq;
    bf16x8 a0 = *((const bf16x8*)&As[wm * 32 + lrow][k0]);
    bf16x8 a1 = *((const bf16x8*)&As[wm * 32 + 16 + lrow][k0]);
#pragma unroll
    for (int ni = 0; ni < 4; ++ni) {
      bf16x8 b = *((const bf16x8*)&Bs[wn * 64 + ni * 16 + lrow][k0]);
      acc[0][ni] = __builtin_amdgcn_mfma_f32_16x16x32_bf16(a0, b, acc[0][ni], 0, 0, 0);
      acc[1][ni] = __builtin_amdgcn_mfma_f32_16x16x32_bf16(a1, b, acc[1][ni], 0, 0, 0);
    }
  }

  const float* bias = biasc + mat * DIM;
  u16* Out; int rstride, coff;
  if (mat == 0)      { Out = Q;  rstride = DIM;     coff = 0;   }
  else if (mat == 1) { Out = KV; rstride = 2 * DIM; coff = 0;   }
  else if (mat == 2) { Out = KV; rstride = 2 * DIM; coff = DIM; }
  else               { Out = S;  rstride = DIM;     coff = 0;   }
#pragma unroll
  for (int mi = 0; mi < 2; ++mi)
#pragma unroll
    for (int ni = 0; ni < 4; ++ni) {
      int colg = wn * 64 + ni * 16 + lrow;
      float bvf = bias[colg];
#pragma unroll
      for (int r = 0; r < 4; ++r) {
        int rowg = r0 + wm * 32 + mi * 16 + (lane >> 4) * 4 + r;
        if (rowg < N_NODES) {
          float o = acc[mi][ni][r] + bvf;
          if (!(o - o == 0.0f)) o = 7000.0f;
          Out[(size_t)rowg * rstride + coff + colg] = f2bf(o);
        }
      }
    }
}

// ---------------- CSR build ----------------
__global__ void count_deg(const int* __restrict__ ei, const int* __restrict__ flags,
                          int* __restrict__ deg) {
  int e = blockIdx.x * 256 + threadIdx.x;
  if (e < N_EDGES) {
    int s, d;
    load_edge(ei, flags[1] == 0, e, s, d);
    atomicAdd(&deg[d], 1);
  }
}

__global__ void scan_blk(const int* __restrict__ deg, int* __restrict__ row_ptr,
                         int* __restrict__ blksum) {
  __shared__ int buf[1024];
  int tid = threadIdx.x;
  int idx = blockIdx.x * 1024 + tid;
  int v = (idx < N_NODES) ? deg[idx] : 0;
  buf[tid] = v;
  __syncthreads();
  for (int off = 1; off < 1024; off <<= 1) {
    int t = (tid >= off) ? buf[tid - off] : 0;
    __syncthreads();
    buf[tid] += t;
    __syncthreads();
  }
  if (idx < N_NODES) row_ptr[idx + 1] = buf[tid];
  if (tid == 1023) blksum[blockIdx.x] = buf[1023];
}

__global__ void scan_sums(int* __restrict__ blksum, int nblk) {
  if (threadIdx.x == 0) {
    int run = 0;
    for (int b = 0; b < nblk; ++b) { int t = blksum[b]; blksum[b] = run; run += t; }
  }
}

__global__ void scan_add(int* __restrict__ row_ptr, const int* __restrict__ blksum) {
  int idx = blockIdx.x * 1024 + threadIdx.x;
  if (idx < N_NODES) row_ptr[idx + 1] += blksum[blockIdx.x];
  if (idx == 0) row_ptr[0] = 0;
}

__global__ void fill_csr(const int* __restrict__ ei, const int* __restrict__ flags,
                         const int* __restrict__ row_ptr, int* __restrict__ deg,
                         int* __restrict__ csr_src) {
  int e = blockIdx.x * 256 + threadIdx.x;
  if (e < N_EDGES) {
    int s, d;
    load_edge(ei, flags[1] == 0, e, s, d);
    int c = atomicSub(&deg[d], 1);
    int pos = row_ptr[d] + c - 1;
    if (pos >= 0 && pos < N_EDGES) csr_src[pos] = s;
  }
}

// ---------------- attention: 1 node / 16-lane group, LDS async prefetch ----------
// Group g owns node blockIdx*16 + wid*4 + g; lane sl covers dims sl*8..+7.
// K/V gather goes through a 4-slot LDS ring per wave (slot = 2 KB), filled by
// global_load_lds at depth 3, drained with a COUNTED s_waitcnt vmcnt(6) (never 0;
// 6 = 2 iterations' 3 VMEM ops each + margin 2 for compiler reordering of the
// per-iteration index load within the zone — in-order vmcnt retirement makes a
// stricter count always safe). ds_read is inline asm (compiler would otherwise
// insert a serializing vmcnt(0) for the LDS-DMA hazard); each ds_read is its own
// asm with "=&v" EARLY-CLOBBER so the output quad can never overlap the other
// read's address register (R6's correctness bug). lgkmcnt(0) + sched_barrier(0)
// fences the consumers (rule #18).
__global__ __launch_bounds__(256, 4) void attn_agg(
    const u16* __restrict__ Q, const u16* __restrict__ KV,
    const u16* __restrict__ S,
    const int* __restrict__ row_ptr, const int* __restrict__ csr_src,
    void* __restrict__ Hout, int apply_relu, int out_f32) {
  __shared__ __align__(16) char smem[32768];   // 4 waves * 4 slots * 2048 B
  int wid = threadIdx.x >> 6;
  int lane = threadIdx.x & 63;
  int g = lane >> 4;            // 0..3  (node slot within wave)
  int sl = lane & 15;           // 0..15 (dim slice)
  int n = blockIdx.x * 16 + wid * 4 + g;
  bool valid = (n < N_NODES);
  int nc = valid ? n : N_NODES - 1;
  int d0 = sl * 8;
  uint4 qv = *((const uint4*)&Q[(size_t)nc * DIM + d0]);
  uint4 sv = *((const uint4*)&S[(size_t)nc * DIM + d0]);
#if !HAS_FDOT2
  float qf[8]; unpack8(qv, qf);
#endif
  int start = row_ptr[nc], end = row_ptr[nc + 1];
  start = min(max(start, 0), N_EDGES);
  end = min(max(end, start), N_EDGES);
  int deg = valid ? (end - start) : 0;
  int imax = deg;
  imax = max(imax, __shfl_xor(imax, 16));
  imax = max(imax, __shfl_xor(imax, 32));

  const float scale2 = 0.1275174319f;   // (1/sqrt(128)) * log2(e)
  float m = -INFINITY, lsum = 0.f;      // state in base-2 units
  float acc[8] = {};

  // clamped edge position: always a valid, written csr_src slot
  int hi = max(start, end - 1);
  hi = min(max(hi, 0), N_EDGES - 1);
  auto CE = [&](int t) { int ec = start + t; ec = (ec > hi) ? hi : ec;
                         return min(max(ec, 0), N_EDGES - 1); };

  lds_char* wbase = ((lds_char*)smem) + wid * 8192;
  const char* KVc = (const char*)KV;
  int sloff = sl * 16;

  int iU = 0, iA = 0, iB = 0;
  if (imax > 0) {
    int j0 = csr_src[CE(0)], j1 = csr_src[CE(1)], j2 = csr_src[CE(2)];
    iU = csr_src[CE(3)]; iA = csr_src[CE(4)]; iB = csr_src[CE(5)];
    int r0 = min(max(j0, 0), N_NODES - 1);
    int r1 = min(max(j1, 0), N_NODES - 1);
    int r2 = min(max(j2, 0), N_NODES - 1);
    gll16(KVc + (size_t)r0 * 512 + sloff,       wbase);
    gll16(KVc + (size_t)r0 * 512 + 256 + sloff, wbase + 1024);
    gll16(KVc + (size_t)r1 * 512 + sloff,       wbase + 2048);
    gll16(KVc + (size_t)r1 * 512 + 256 + sloff, wbase + 2048 + 1024);
    gll16(KVc + (size_t)r2 * 512 + sloff,       wbase + 4096);
    gll16(KVc + (size_t)r2 * 512 + 256 + sloff, wbase + 4096 + 1024);
  }

  for (int i = 0; i < imax; ++i) {
    // (a) index prefetch for iter i+6 (becomes iU at iter i+3)
    int iN = csr_src[CE(i + 6)];
    // (b) issue async fill of slot i+3 using iU = idx(i+3)
    int row = min(max(iU, 0), N_NODES - 1);
    const char* src = KVc + (size_t)row * 512 + sloff;
    lds_char* wslot = wbase + ((i + 3) & 3) * 2048;
    gll16(src, wslot);
    gll16(src + 256, wslot + 1024);
    // (c) counted drain: guarantees slot i's 2 fills retired (in-order vmcnt)
    asm volatile("s_waitcnt vmcnt(6)" ::: "memory");
    u32 rdK = (u32)(uintptr_t)(wbase + (i & 3) * 2048) + (u32)lane * 16u;
    u32 rdV = rdK + 1024u;
    uint4 kq, vq;
    asm volatile("ds_read_b128 %0, %1" : "=&v"(kq) : "v"(rdK));
    asm volatile("ds_read_b128 %0, %1" : "=&v"(vq) : "v"(rdV));
    asm volatile("s_waitcnt lgkmcnt(0)");
    __builtin_amdgcn_sched_barrier(0);

    // ---- PROC ----
    float p;
#if HAS_FDOT2
    union U { u32 u; bf16x2 b; };
    U a0{qv.x}, a1{qv.y}, a2{qv.z}, a3{qv.w};
    U b0{kq.x}, b1{kq.y}, b2{kq.z}, b3{kq.w};
    p = __builtin_amdgcn_fdot2_f32_bf16(a0.b, b0.b, 0.0f, false);
    p = __builtin_amdgcn_fdot2_f32_bf16(a1.b, b1.b, p, false);
    p = __builtin_amdgcn_fdot2_f32_bf16(a2.b, b2.b, p, false);
    p = __builtin_amdgcn_fdot2_f32_bf16(a3.b, b3.b, p, false);
#else
    float kf[8]; unpack8(kq, kf);
    p = qf[0] * kf[0] + qf[1] * kf[1] + qf[2] * kf[2] + qf[3] * kf[3]
      + qf[4] * kf[4] + qf[5] * kf[5] + qf[6] * kf[6] + qf[7] * kf[7];
#endif
    p = dpp_add<0xB1>(p);    // quad_perm [1,0,3,2]
    p = dpp_add<0x4E>(p);    // quad_perm [2,3,0,1]
    p = dpp_add<0x124>(p);   // row_ror:4
    p = dpp_add<0x128>(p);   // row_ror:8
    float s2 = p * scale2;               // uniform within the 16-lane group
    float vf[8]; unpack8(vq, vf);
    bool act = (i < deg);
    if (act && (s2 - m > 11.0f)) {       // new max (first active edge lands here)
      float wold = __builtin_amdgcn_exp2f(m - s2);   // exp2(-inf)=0 first edge
      lsum = fmaf(lsum, wold, 1.0f);
#pragma unroll
      for (int j = 0; j < 8; ++j) acc[j] = fmaf(acc[j], wold, vf[j]);
      m = s2;
    } else {                             // common path (or inactive: wv=0)
      float wv = act ? __builtin_amdgcn_exp2f(s2 - m) : 0.0f;
      lsum += wv;
#pragma unroll
      for (int j = 0; j < 8; ++j) acc[j] = fmaf(wv, vf[j], acc[j]);
    }
    iU = iA; iA = iB; iB = iN;
  }

  // per-group softmax state is complete (no cross-group merge)
  float inv = (lsum > 0.f) ? (1.0f / lsum) : 0.f;
  float sf[8]; unpack8(sv, sf);
  float o[8];
#pragma unroll
  for (int j = 0; j < 8; ++j) {
    float v = acc[j] * inv + sf[j];
    if (apply_relu) v = (v >= 0.f) ? v : 0.01f * v;
    if (!(v - v == 0.0f)) v = 9000.0f;
    o[j] = v;
  }
  if (valid) {
    if (out_f32) {
      float* H = (float*)Hout;
      *((float4*)&H[(size_t)n * DIM + d0]) = make_float4(o[0], o[1], o[2], o[3]);
      *((float4*)&H[(size_t)n * DIM + d0 + 4]) = make_float4(o[4], o[5], o[6], o[7]);
    } else {
      union { u16 h[8]; uint4 q; } pk;
#pragma unroll
      for (int j = 0; j < 8; ++j) pk.h[j] = f2bf(o[j]);
      *((uint4*)&((u16*)Hout)[(size_t)n * DIM + d0]) = pk.q;
    }
  }
}

// ---------------- parallel mean pool ----------------
__device__ __forceinline__ int bat_at(const int* bat, int i, bool is64) {
  return is64 ? (int)((const i64*)bat)[i] : bat[i];
}

__global__ __launch_bounds__(128) void pool_partial(
    const float* __restrict__ node_emb, const int* __restrict__ bat,
    const int* __restrict__ flags, float* __restrict__ gsum, float* __restrict__ gcnt) {
  int t = threadIdx.x;
  int r0 = blockIdx.x * POOL_ROWS;
  int rend = min(r0 + POOL_ROWS, N_NODES);
  if (r0 >= rend) return;
  bool is64 = (flags[2] == 0);
  int cur = min(max(bat_at(bat, r0, is64), 0), NGRAPH - 1);
  float acc = 0.f;
  int cnt = 0;
  for (int i = r0; i < rend; ++i) {
    int b = min(max(bat_at(bat, i, is64), 0), NGRAPH - 1);
    if (b != cur) {
      atomicAdd(&gsum[cur * DIM + t], acc);
      if (t == 0) atomicAdd(&gcnt[cur], (float)cnt);
      acc = 0.f; cnt = 0; cur = b;
    }
    acc += node_emb[(size_t)i * DIM + t];
    ++cnt;
  }
  atomicAdd(&gsum[cur * DIM + t], acc);
  if (t == 0) atomicAdd(&gcnt[cur], (float)cnt);
}

__global__ void pool_final(const float* __restrict__ gsum, const float* __restrict__ gcnt,
                           float* __restrict__ graph_emb) {
  int i = blockIdx.x * 256 + threadIdx.x;
  if (i < NGRAPH * DIM) {
    int b = i >> 7;
    float g = gsum[i] / fmaxf(gcnt[b], 1.0f);
    if (!(g - g == 0.0f)) g = 5555.0f;
    graph_emb[i] = g;
  }
}

extern "C" void kernel_launch(void* const* d_in, const int* in_sizes, int n_in,
                              void* d_out, int out_size, void* d_ws, size_t ws_size,
                              hipStream_t stream) {
  static const int EXP_SIZES[11] = {6400000, 1200000, 50000,
                                    49152, 384, 49152, 384, 49152, 384, 49152, 384};
  {
    float code = 0.0f;
    if (n_in != 11) code = 40000.0f;
    else if (out_size != 6416384) code = 42000.0f;
    else {
      for (int i = 0; i < 11; ++i)
        if (in_sizes[i] != EXP_SIZES[i]) { code = 44000.0f + 400.0f * i; break; }
    }
    if (code != 0.0f) {
      sentinel_fill<<<(out_size + 255) / 256, 256, 0, stream>>>((float*)d_out, out_size, code);
      return;
    }
  }

  const u16* x   = (const u16*)d_in[0];
  const int* ei  = (const int*)d_in[1];
  const int* bat = (const int*)d_in[2];

  const size_t NEEDED = 54465936;
  if (ws_size < NEEDED) {
    float code = 1000.0f + (float)(ws_size >> 20);
    sentinel_fill<<<(out_size + 255) / 256, 256, 0, stream>>>((float*)d_out, out_size, code);
    return;
  }

  char* w = (char*)d_ws;
  int*   flags   = (int*)w;   w += 256;
  int*   blksum  = (int*)w;   w += 256;
  float* gsum    = (float*)w; w += (size_t)NGRAPH * DIM * 4;
  float* gcnt    = (float*)w; w += (size_t)NGRAPH * 4;
  int*   deg     = (int*)w;   w += (size_t)N_NODES * 4;
  int*   row_ptr = (int*)w;   w += (size_t)(N_NODES + 4) * 4;
  int*   csr_src = (int*)w;   w += (size_t)N_EDGES * 4;
  u16*   WT      = (u16*)w;   w += (size_t)12 * DIM * DIM * 2;
  float* biasc   = (float*)w; w += (size_t)12 * DIM * 4;
  const size_t ND2 = (size_t)N_NODES * DIM * 2;
  u16* Qb  = (u16*)w; w += ND2;
  u16* KVb = (u16*)w; w += 2 * ND2;   // interleaved [K|V] per node
  u16* Sb  = (u16*)w; w += ND2;

  hipMemsetAsync(flags, 0, 512 + 65536 + 512 + (size_t)N_NODES * 4, stream);

  detect_dtypes<<<128, 256, 0, stream>>>(x, ei, bat, flags);
  prep_wt<<<12, 256, 0, stream>>>(d_in[3], d_in[5], d_in[7], d_in[9], WT, flags);
  canon_bias<<<1, 256, 0, stream>>>(d_in[4], d_in[6], d_in[8], d_in[10], biasc, flags);

  u16* Hb = (u16*)d_out;   // bf16 h aliases d_out node region (fp32) — safe, see R11
  convert_x<<<(N_NODES * DIM / 8 + 255) / 256, 256, 0, stream>>>(x, flags, Hb);

  int eblocks = (N_EDGES + 255) / 256;
  int nblk = (N_NODES + 1023) / 1024;   // 49
  count_deg<<<eblocks, 256, 0, stream>>>(ei, flags, deg);
  scan_blk<<<nblk, 1024, 0, stream>>>(deg, row_ptr, blksum);
  scan_sums<<<1, 64, 0, stream>>>(blksum, nblk);
  scan_add<<<nblk, 1024, 0, stream>>>(row_ptr, blksum);
  fill_csr<<<eblocks, 256, 0, stream>>>(ei, flags, row_ptr, deg, csr_src);

  float* node_out = (float*)d_out;
  for (int l = 0; l < 3; ++l) {
    gemm_qkvs<<<dim3((N_NODES + 63) / 64, 4), 256, 0, stream>>>(
        Hb, WT + (size_t)l * 4 * DIM * DIM, biasc + (size_t)l * 4 * DIM,
        Qb, KVb, Sb);
    if (l < 2)
      attn_agg<<<(N_NODES + 15) / 16, 256, 0, stream>>>(Qb, KVb, Sb, row_ptr, csr_src,
                                                        (void*)Hb, 1, 0);
    else
      attn_agg<<<(N_NODES + 15) / 16, 256, 0, stream>>>(Qb, KVb, Sb, row_ptr, csr_src,
                                                        (void*)node_out, 0, 1);
  }
  int pblocks = (N_NODES + POOL_ROWS - 1) / POOL_ROWS;   // 500
  pool_partial<<<pblocks, 128, 0, stream>>>(node_out, bat, flags, gsum, gcnt);
  pool_final<<<(NGRAPH * DIM + 255) / 256, 256, 0, stream>>>(gsum, gcnt,
                                                             node_out + (size_t)N_NODES * DIM);
}